// Round 1
// baseline (192.105 us; speedup 1.0000x reference)
//
#include <hip/hip_runtime.h>

// Grapher block (DeepGCN MRConv) on MI355X, fp32 correctness-first version.
// Pipeline: fc1(Conv1d k=1)+BN+ReLU -> gather/max-diff -> cat -> FC(2Cx2C)+ReLU
//           -> fc2(Conv1d k=1)+BN -> +residual -> ReLU
// Scratch layout in d_ws: xn[32768][128] fp32 (16MB), hn[32768][256] fp32 (32MB).

namespace {
constexpr int Bn = 8;
constexpr int Cc = 128;
constexpr int Nn = 4096;
constexpr int Kk = 16;
constexpr int C2 = 256;
constexpr int NODES = Bn * Nn;
constexpr float EPSf = 1e-5f;
}

__device__ __forceinline__ float f4get(const float4& v, int d) {
    return d == 0 ? v.x : d == 1 ? v.y : d == 2 ? v.z : v.w;
}

// ---------------------------------------------------------------------------
// K1: xn[node][o] = relu( (W1@x)*s1 + (b1-m1)*s1 + be1 )
// block: 256 thr, tile = (b fixed, 64 n, all 128 o)
// ---------------------------------------------------------------------------
__global__ __launch_bounds__(256) void fc1_kernel(
    const float* __restrict__ x, const float* __restrict__ W1,
    const float* __restrict__ b1, const float* __restrict__ g1,
    const float* __restrict__ be1, const float* __restrict__ m1,
    const float* __restrict__ v1, float* __restrict__ xn)
{
    __shared__ __align__(16) float xS[Cc * 68];   // [c][64n] pad->68
    __shared__ __align__(16) float W1S[Cc * 36];  // [o][32c] pad->36
    const int t  = threadIdx.x;
    const int n0 = blockIdx.x * 64;
    const int b  = blockIdx.y;

    // stage x tile [128c][64n]
    {
        const int c = t >> 1, h = t & 1;
        const float* sp = x + (b * Cc + c) * Nn + n0 + h * 32;
        float* dp = &xS[c * 68 + h * 32];
        #pragma unroll
        for (int j = 0; j < 8; ++j)
            *(float4*)(dp + j * 4) = *(const float4*)(sp + j * 4);
    }

    const int og = t & 31, ng = t >> 5;  // o = og+32*oo, n = ng*8+nn
    float acc[4][8];
    #pragma unroll
    for (int a = 0; a < 4; ++a)
        #pragma unroll
        for (int q = 0; q < 8; ++q) acc[a][q] = 0.f;

    for (int cc = 0; cc < 4; ++cc) {
        __syncthreads();
        // stage W1 chunk [128o][32c]
        {
            const int o = t >> 1, h = t & 1;
            const float* sp = W1 + o * Cc + cc * 32 + h * 16;
            float* dp = &W1S[o * 36 + h * 16];
            #pragma unroll
            for (int j = 0; j < 4; ++j)
                *(float4*)(dp + j * 4) = *(const float4*)(sp + j * 4);
        }
        __syncthreads();
        #pragma unroll
        for (int i4 = 0; i4 < 8; ++i4) {
            float4 w[4];
            #pragma unroll
            for (int oo = 0; oo < 4; ++oo)
                w[oo] = *(const float4*)&W1S[(og + 32 * oo) * 36 + i4 * 4];
            #pragma unroll
            for (int d = 0; d < 4; ++d) {
                const int c = cc * 32 + i4 * 4 + d;
                const float4 xlo = *(const float4*)&xS[c * 68 + ng * 8];
                const float4 xhi = *(const float4*)&xS[c * 68 + ng * 8 + 4];
                #pragma unroll
                for (int oo = 0; oo < 4; ++oo) {
                    const float wd = f4get(w[oo], d);
                    acc[oo][0] += wd * xlo.x;
                    acc[oo][1] += wd * xlo.y;
                    acc[oo][2] += wd * xlo.z;
                    acc[oo][3] += wd * xlo.w;
                    acc[oo][4] += wd * xhi.x;
                    acc[oo][5] += wd * xhi.y;
                    acc[oo][6] += wd * xhi.z;
                    acc[oo][7] += wd * xhi.w;
                }
            }
        }
    }

    #pragma unroll
    for (int oo = 0; oo < 4; ++oo) {
        const int o = og + 32 * oo;
        const float s  = g1[o] * rsqrtf(v1[o] + EPSf);
        const float tt = (b1[o] - m1[o]) * s + be1[o];
        #pragma unroll
        for (int nn = 0; nn < 8; ++nn) {
            float vv = acc[oo][nn] * s + tt;
            vv = vv > 0.f ? vv : 0.f;
            const int n = n0 + ng * 8 + nn;
            xn[(size_t)(b * Nn + n) * Cc + o] = vv;
        }
    }
}

// ---------------------------------------------------------------------------
// K2+K3 fused: per 64-node tile: gather K=16 src rows, cat=[xn, xn-min_k],
// then hn[node][j] = relu(sum_i Wmr[j][i]*cat[node][i] + bmr[j])
// ---------------------------------------------------------------------------
__global__ __launch_bounds__(256) void mr_kernel(
    const float* __restrict__ xn, const int* __restrict__ src,
    const float* __restrict__ Wmr, const float* __restrict__ bmr,
    float* __restrict__ hn)
{
    __shared__ __align__(16) float catS[64 * 260];   // [node][256] pad->260
    __shared__ __align__(16) float WmrS[C2 * 36];    // [j][32i] pad->36
    const int t = threadIdx.x;
    const int node0 = blockIdx.x * 64;

    // gather + min + build cat tile. 4 threads/node, 32 channels each.
    {
        const int nl = t >> 2, q = t & 3;
        const int node = node0 + nl;
        const float* op = xn + (size_t)node * Cc + q * 32;
        float4 own[8], mn[8];
        #pragma unroll
        for (int j = 0; j < 8; ++j) own[j] = *(const float4*)(op + j * 4);
        {
            const int idx = src[node * Kk];
            const float* sp = xn + (size_t)idx * Cc + q * 32;
            #pragma unroll
            for (int j = 0; j < 8; ++j) mn[j] = *(const float4*)(sp + j * 4);
        }
        for (int k = 1; k < Kk; ++k) {
            const int idx = src[node * Kk + k];
            const float* sp = xn + (size_t)idx * Cc + q * 32;
            #pragma unroll
            for (int j = 0; j < 8; ++j) {
                const float4 v = *(const float4*)(sp + j * 4);
                mn[j].x = fminf(mn[j].x, v.x);
                mn[j].y = fminf(mn[j].y, v.y);
                mn[j].z = fminf(mn[j].z, v.z);
                mn[j].w = fminf(mn[j].w, v.w);
            }
        }
        #pragma unroll
        for (int j = 0; j < 8; ++j) {
            *(float4*)&catS[nl * 260 + q * 32 + j * 4] = own[j];
            float4 df;
            df.x = own[j].x - mn[j].x;
            df.y = own[j].y - mn[j].y;
            df.z = own[j].z - mn[j].z;
            df.w = own[j].w - mn[j].w;
            *(float4*)&catS[nl * 260 + 128 + q * 32 + j * 4] = df;
        }
    }

    const int jg = t & 31, ng = t >> 5;  // j = jg+32*jj, n = ng*8+nn
    float acc[8][8];
    #pragma unroll
    for (int a = 0; a < 8; ++a)
        #pragma unroll
        for (int q = 0; q < 8; ++q) acc[a][q] = 0.f;

    for (int ic = 0; ic < 8; ++ic) {
        __syncthreads();
        // stage Wmr chunk [256j][32i] (row per thread)
        {
            const float* sp = Wmr + (size_t)t * C2 + ic * 32;
            float* dp = &WmrS[t * 36];
            #pragma unroll
            for (int j = 0; j < 8; ++j)
                *(float4*)(dp + j * 4) = *(const float4*)(sp + j * 4);
        }
        __syncthreads();
        #pragma unroll
        for (int i4 = 0; i4 < 8; ++i4) {
            float4 w[8];
            #pragma unroll
            for (int jj = 0; jj < 8; ++jj)
                w[jj] = *(const float4*)&WmrS[(jg + 32 * jj) * 36 + i4 * 4];
            float4 ca[8];
            #pragma unroll
            for (int nn = 0; nn < 8; ++nn)
                ca[nn] = *(const float4*)&catS[(ng * 8 + nn) * 260 + ic * 32 + i4 * 4];
            #pragma unroll
            for (int jj = 0; jj < 8; ++jj)
                #pragma unroll
                for (int nn = 0; nn < 8; ++nn) {
                    acc[jj][nn] += w[jj].x * ca[nn].x;
                    acc[jj][nn] += w[jj].y * ca[nn].y;
                    acc[jj][nn] += w[jj].z * ca[nn].z;
                    acc[jj][nn] += w[jj].w * ca[nn].w;
                }
        }
    }

    #pragma unroll
    for (int jj = 0; jj < 8; ++jj) {
        const int j = jg + 32 * jj;
        const float bb = bmr[j];
        #pragma unroll
        for (int nn = 0; nn < 8; ++nn) {
            float vv = acc[jj][nn] + bb;
            vv = vv > 0.f ? vv : 0.f;
            hn[(size_t)(node0 + ng * 8 + nn) * C2 + j] = vv;
        }
    }
}

// ---------------------------------------------------------------------------
// K4: out[b][o][n] = relu( (W2@hn)*s2 + (b2-m2)*s2 + be2 + x[b][o][n] )
// ---------------------------------------------------------------------------
__global__ __launch_bounds__(256) void fc2_kernel(
    const float* __restrict__ hn, const float* __restrict__ x,
    const float* __restrict__ W2, const float* __restrict__ b2,
    const float* __restrict__ g2, const float* __restrict__ be2,
    const float* __restrict__ m2, const float* __restrict__ v2,
    float* __restrict__ out)
{
    __shared__ __align__(16) float hnS[64 * 260];  // [node][256] pad->260
    __shared__ __align__(16) float W2S[Cc * 20];   // [o][16j] pad->20
    const int t  = threadIdx.x;
    const int n0 = blockIdx.x * 64;
    const int b  = blockIdx.y;
    const int node0 = b * Nn + n0;

    // stage hn tile [64 node][256 j]
    {
        const int nl = t >> 2, q = t & 3;
        const float* sp = hn + (size_t)(node0 + nl) * C2 + q * 64;
        float* dp = &hnS[nl * 260 + q * 64];
        #pragma unroll
        for (int j = 0; j < 16; ++j)
            *(float4*)(dp + j * 4) = *(const float4*)(sp + j * 4);
    }

    const int og = t & 31, ng = t >> 5;  // o = og+32*oo, n = ng*8+nn
    float acc[4][8];
    #pragma unroll
    for (int a = 0; a < 4; ++a)
        #pragma unroll
        for (int q = 0; q < 8; ++q) acc[a][q] = 0.f;

    for (int jc = 0; jc < 16; ++jc) {
        __syncthreads();
        // stage W2 chunk [128o][16j]
        {
            const int o = t >> 1, h = t & 1;
            const float* sp = W2 + (size_t)o * C2 + jc * 16 + h * 8;
            float* dp = &W2S[o * 20 + h * 8];
            #pragma unroll
            for (int j = 0; j < 2; ++j)
                *(float4*)(dp + j * 4) = *(const float4*)(sp + j * 4);
        }
        __syncthreads();
        #pragma unroll
        for (int i4 = 0; i4 < 4; ++i4) {
            float4 w[4];
            #pragma unroll
            for (int oo = 0; oo < 4; ++oo)
                w[oo] = *(const float4*)&W2S[(og + 32 * oo) * 20 + i4 * 4];
            float4 ha[8];
            #pragma unroll
            for (int nn = 0; nn < 8; ++nn)
                ha[nn] = *(const float4*)&hnS[(ng * 8 + nn) * 260 + jc * 16 + i4 * 4];
            #pragma unroll
            for (int oo = 0; oo < 4; ++oo)
                #pragma unroll
                for (int nn = 0; nn < 8; ++nn) {
                    acc[oo][nn] += w[oo].x * ha[nn].x;
                    acc[oo][nn] += w[oo].y * ha[nn].y;
                    acc[oo][nn] += w[oo].z * ha[nn].z;
                    acc[oo][nn] += w[oo].w * ha[nn].w;
                }
        }
    }

    #pragma unroll
    for (int oo = 0; oo < 4; ++oo) {
        const int o = og + 32 * oo;
        const float s  = g2[o] * rsqrtf(v2[o] + EPSf);
        const float tt = (b2[o] - m2[o]) * s + be2[o];
        const float* xr = x   + (size_t)(b * Cc + o) * Nn + n0 + ng * 8;
        float*       orp = out + (size_t)(b * Cc + o) * Nn + n0 + ng * 8;
        #pragma unroll
        for (int nn = 0; nn < 8; ++nn) {
            float vv = acc[oo][nn] * s + tt + xr[nn];
            vv = vv > 0.f ? vv : 0.f;
            orp[nn] = vv;
        }
    }
}

// ---------------------------------------------------------------------------
extern "C" void kernel_launch(void* const* d_in, const int* in_sizes, int n_in,
                              void* d_out, int out_size, void* d_ws, size_t ws_size,
                              hipStream_t stream)
{
    const float* x   = (const float*)d_in[0];
    const int*   src = (const int*)  d_in[1];
    const float* W1  = (const float*)d_in[2];
    const float* b1  = (const float*)d_in[3];
    const float* g1  = (const float*)d_in[4];
    const float* be1 = (const float*)d_in[5];
    const float* m1  = (const float*)d_in[6];
    const float* v1  = (const float*)d_in[7];
    const float* Wmr = (const float*)d_in[8];
    const float* bmr = (const float*)d_in[9];
    const float* W2  = (const float*)d_in[10];
    const float* b2  = (const float*)d_in[11];
    const float* g2  = (const float*)d_in[12];
    const float* be2 = (const float*)d_in[13];
    const float* m2  = (const float*)d_in[14];
    const float* v2  = (const float*)d_in[15];
    float* out = (float*)d_out;

    float* xn = (float*)d_ws;                    // [NODES][128]
    float* hn = xn + (size_t)NODES * Cc;         // [NODES][256]

    const dim3 blk(256);
    fc1_kernel<<<dim3(Nn / 64, Bn), blk, 0, stream>>>(x, W1, b1, g1, be1, m1, v1, xn);
    mr_kernel<<<dim3(NODES / 64), blk, 0, stream>>>(xn, src, Wmr, bmr, hn);
    fc2_kernel<<<dim3(Nn / 64, Bn), blk, 0, stream>>>(hn, x, W2, b2, g2, be2, m2, v2, out);
}

// Round 2
// 61.003 us; speedup vs baseline: 3.1491x; 3.1491x over previous
//
#include <hip/hip_runtime.h>

// Grapher block (DeepGCN MRConv) on MI355X — bf16 MFMA version.
// fc1(Conv1d k=1)+BN+ReLU -> gather/min/diff/cat -> FC(2Cx2C)+ReLU -> fc2+BN+res+ReLU
// Scratch (d_ws): W1bf(32K) Wmrbf(128K) W2bf(64K), xn bf16 [32768][128] (8MB),
//                 hn bf16 [32768][256] (16MB).  Total ~24.3 MB.
//
// MFMA 16x16x32 bf16 layout (guide §3, m89-verified):
//   A: row = lane&15, k = (lane>>4)*8 + j   (bf16x8 contiguous in k)
//   B: col = lane&15, k = (lane>>4)*8 + j
//   D: col = lane&15, row = (lane>>4)*4 + r

typedef short bf8_t __attribute__((ext_vector_type(8)));
typedef float f4_t  __attribute__((ext_vector_type(4)));

namespace {
constexpr int Bn = 8, Cc = 128, Nn = 4096, Kk = 16, C2 = 256;
constexpr int NODES = Bn * Nn;
constexpr float EPSf = 1e-5f;
}

__device__ __forceinline__ unsigned short f2bf(float f) {
    unsigned u = __float_as_uint(f);
    u += 0x7fffu + ((u >> 16) & 1u);   // RNE; NaN impossible in our data path
    return (unsigned short)(u >> 16);
}
__device__ __forceinline__ float bflo(unsigned u) { return __uint_as_float(u << 16); }
__device__ __forceinline__ float bfhi(unsigned u) { return __uint_as_float(u & 0xffff0000u); }
__device__ __forceinline__ unsigned diff2(unsigned o, unsigned m) {
    const float lo = bflo(o) - bflo(m);
    const float hi = bfhi(o) - bfhi(m);
    return (unsigned)f2bf(lo) | ((unsigned)f2bf(hi) << 16);
}

// packed u16 min: valid as bf16-min because all gathered values are >= 0 (post-ReLU)
#define PKMIN(a, b) asm("v_pk_min_u16 %0, %0, %1" : "+v"(a) : "v"(b))

// ---------------------------------------------------------------------------
// prep: convert W1 / Wmr / W2 fp32 -> bf16 row-major (one-time per launch)
// ---------------------------------------------------------------------------
__global__ __launch_bounds__(256) void prep_kernel(
    const float* __restrict__ W1, const float* __restrict__ Wmr,
    const float* __restrict__ W2, ushort* __restrict__ W1bf,
    ushort* __restrict__ Wmrbf, ushort* __restrict__ W2bf)
{
    const int e = (blockIdx.x * 256 + threadIdx.x) * 4;  // 114688 elems total
    const float* s;
    ushort* d;
    if (e < 16384)      { s = W1 + e;          d = W1bf + e; }
    else if (e < 81920) { s = Wmr + (e-16384); d = Wmrbf + (e-16384); }
    else                { s = W2 + (e-81920);  d = W2bf + (e-81920); }
    const float4 v = *(const float4*)s;
    ushort4 r;
    r.x = f2bf(v.x); r.y = f2bf(v.y); r.z = f2bf(v.z); r.w = f2bf(v.w);
    *(ushort4*)d = r;
}

// ---------------------------------------------------------------------------
// fc1: xn[n][o] = relu( BN( sum_c W1[o][c]*x[b][c][n] ) )   (D rows=n, cols=o)
// block: 256 thr = 4 waves (2x2), tile 128 nodes x 128 o
// ---------------------------------------------------------------------------
__global__ __launch_bounds__(256) void fc1_mfma(
    const float* __restrict__ x, const ushort* __restrict__ W1bf,
    const float* __restrict__ b1, const float* __restrict__ g1,
    const float* __restrict__ be1, const float* __restrict__ m1,
    const float* __restrict__ v1, ushort* __restrict__ xn)
{
    __shared__ float scS[Cc], shS[Cc];
    const int t = threadIdx.x;
    if (t < Cc) {
        const float s = g1[t] * rsqrtf(v1[t] + EPSf);
        scS[t] = s;
        shS[t] = (b1[t] - m1[t]) * s + be1[t];
    }
    __syncthreads();

    const int nt0 = blockIdx.x * 128;
    const int b  = nt0 >> 12;
    const int n0 = nt0 & 4095;
    const int w = t >> 6, lane = t & 63;
    const int row16 = lane & 15, kg = lane >> 4;
    const int wr = w >> 1, wc = w & 1;   // wr: node half, wc: o half
    const float* xb = x + (size_t)b * Cc * Nn;

    f4_t acc[4][4];  // [nsub][osub]
    const f4_t zero = {0.f, 0.f, 0.f, 0.f};
    #pragma unroll
    for (int i = 0; i < 4; ++i)
        #pragma unroll
        for (int j = 0; j < 4; ++j) acc[i][j] = zero;

    #pragma unroll
    for (int ks = 0; ks < 4; ++ks) {
        const int c0 = ks * 32 + kg * 8;
        bf8_t af[4];
        #pragma unroll
        for (int nsub = 0; nsub < 4; ++nsub) {
            const float* xp = xb + (size_t)c0 * Nn + (n0 + wr * 64 + nsub * 16 + row16);
            bf8_t a;
            #pragma unroll
            for (int j = 0; j < 8; ++j) a[j] = (short)f2bf(xp[(size_t)j * Nn]);
            af[nsub] = a;
        }
        bf8_t bw[4];
        #pragma unroll
        for (int osub = 0; osub < 4; ++osub) {
            const int o = wc * 64 + osub * 16 + row16;
            bw[osub] = *(const bf8_t*)(W1bf + o * Cc + c0);
        }
        #pragma unroll
        for (int nsub = 0; nsub < 4; ++nsub)
            #pragma unroll
            for (int osub = 0; osub < 4; ++osub)
                acc[nsub][osub] = __builtin_amdgcn_mfma_f32_16x16x32_bf16(
                    af[nsub], bw[osub], acc[nsub][osub], 0, 0, 0);
    }

    #pragma unroll
    for (int osub = 0; osub < 4; ++osub) {
        const int o = wc * 64 + osub * 16 + row16;
        const float s = scS[o], sh = shS[o];
        #pragma unroll
        for (int nsub = 0; nsub < 4; ++nsub)
            #pragma unroll
            for (int r = 0; r < 4; ++r) {
                const int node = nt0 + wr * 64 + nsub * 16 + kg * 4 + r;
                float v = acc[nsub][osub][r] * s + sh;
                v = v > 0.f ? v : 0.f;
                xn[(size_t)node * Cc + o] = f2bf(v);
            }
    }
}

// ---------------------------------------------------------------------------
// mr: cat = [xn | xn - min_k xn[src]] ; hn[n][j] = relu(cat @ Wmr^T + bmr)
// block: 256 thr = 4 waves, tile 64 nodes x 256 j (wave w -> j band 64w)
// ---------------------------------------------------------------------------
__global__ __launch_bounds__(256) void mr_mfma(
    const ushort* __restrict__ xn, const int* __restrict__ src,
    const ushort* __restrict__ Wmrbf, const float* __restrict__ bmr,
    ushort* __restrict__ hn)
{
    __shared__ __align__(16) ushort catS[64 * 264];  // [node][256] pad->264 (2-way=free)
    __shared__ int srcS[64 * Kk];
    const int t = threadIdx.x;
    const int node0 = blockIdx.x * 64;

    ((int4*)srcS)[t] = ((const int4*)(src + (size_t)node0 * Kk))[t];
    __syncthreads();

    {   // gather + u16-min + diff; 4 threads/node, 32 channels each
        const int nl = t >> 2, q = t & 3;
        const ushort* orow = xn + (size_t)(node0 + nl) * Cc + q * 32;
        uint4 ow0 = *(const uint4*)(orow +  0);
        uint4 ow1 = *(const uint4*)(orow +  8);
        uint4 ow2 = *(const uint4*)(orow + 16);
        uint4 ow3 = *(const uint4*)(orow + 24);
        const int* sl = srcS + nl * Kk;
        const ushort* sr = xn + (size_t)sl[0] * Cc + q * 32;
        uint4 mn0 = *(const uint4*)(sr +  0);
        uint4 mn1 = *(const uint4*)(sr +  8);
        uint4 mn2 = *(const uint4*)(sr + 16);
        uint4 mn3 = *(const uint4*)(sr + 24);
        #pragma unroll
        for (int k = 1; k < Kk; ++k) {
            const ushort* s = xn + (size_t)sl[k] * Cc + q * 32;
            uint4 v0 = *(const uint4*)(s +  0);
            uint4 v1 = *(const uint4*)(s +  8);
            uint4 v2 = *(const uint4*)(s + 16);
            uint4 v3 = *(const uint4*)(s + 24);
            PKMIN(mn0.x, v0.x); PKMIN(mn0.y, v0.y); PKMIN(mn0.z, v0.z); PKMIN(mn0.w, v0.w);
            PKMIN(mn1.x, v1.x); PKMIN(mn1.y, v1.y); PKMIN(mn1.z, v1.z); PKMIN(mn1.w, v1.w);
            PKMIN(mn2.x, v2.x); PKMIN(mn2.y, v2.y); PKMIN(mn2.z, v2.z); PKMIN(mn2.w, v2.w);
            PKMIN(mn3.x, v3.x); PKMIN(mn3.y, v3.y); PKMIN(mn3.z, v3.z); PKMIN(mn3.w, v3.w);
        }
        unsigned* crow = (unsigned*)(catS + nl * 264);
        *(uint4*)(crow + q * 16 +  0) = ow0;
        *(uint4*)(crow + q * 16 +  4) = ow1;
        *(uint4*)(crow + q * 16 +  8) = ow2;
        *(uint4*)(crow + q * 16 + 12) = ow3;
        uint4 d0, d1, d2, d3;
        d0.x = diff2(ow0.x, mn0.x); d0.y = diff2(ow0.y, mn0.y); d0.z = diff2(ow0.z, mn0.z); d0.w = diff2(ow0.w, mn0.w);
        d1.x = diff2(ow1.x, mn1.x); d1.y = diff2(ow1.y, mn1.y); d1.z = diff2(ow1.z, mn1.z); d1.w = diff2(ow1.w, mn1.w);
        d2.x = diff2(ow2.x, mn2.x); d2.y = diff2(ow2.y, mn2.y); d2.z = diff2(ow2.z, mn2.z); d2.w = diff2(ow2.w, mn2.w);
        d3.x = diff2(ow3.x, mn3.x); d3.y = diff2(ow3.y, mn3.y); d3.z = diff2(ow3.z, mn3.z); d3.w = diff2(ow3.w, mn3.w);
        *(uint4*)(crow + 64 + q * 16 +  0) = d0;
        *(uint4*)(crow + 64 + q * 16 +  4) = d1;
        *(uint4*)(crow + 64 + q * 16 +  8) = d2;
        *(uint4*)(crow + 64 + q * 16 + 12) = d3;
    }
    __syncthreads();

    const int w = t >> 6, lane = t & 63;
    const int row16 = lane & 15, kg = lane >> 4;
    const int jb = w * 64;

    f4_t acc[4][4];  // [nsub][jsub]
    const f4_t zero = {0.f, 0.f, 0.f, 0.f};
    #pragma unroll
    for (int i = 0; i < 4; ++i)
        #pragma unroll
        for (int j = 0; j < 4; ++j) acc[i][j] = zero;

    #pragma unroll
    for (int ks = 0; ks < 8; ++ks) {
        const int k0 = ks * 32 + kg * 8;
        bf8_t a0 = *(const bf8_t*)(catS + ( 0 + row16) * 264 + k0);
        bf8_t a1 = *(const bf8_t*)(catS + (16 + row16) * 264 + k0);
        bf8_t a2 = *(const bf8_t*)(catS + (32 + row16) * 264 + k0);
        bf8_t a3 = *(const bf8_t*)(catS + (48 + row16) * 264 + k0);
        const ushort* wrow = Wmrbf + (size_t)(jb + row16) * C2 + k0;
        bf8_t b0 = *(const bf8_t*)(wrow);
        bf8_t b1 = *(const bf8_t*)(wrow + 16 * C2);
        bf8_t b2 = *(const bf8_t*)(wrow + 32 * C2);
        bf8_t b3 = *(const bf8_t*)(wrow + 48 * C2);
        acc[0][0] = __builtin_amdgcn_mfma_f32_16x16x32_bf16(a0, b0, acc[0][0], 0, 0, 0);
        acc[0][1] = __builtin_amdgcn_mfma_f32_16x16x32_bf16(a0, b1, acc[0][1], 0, 0, 0);
        acc[0][2] = __builtin_amdgcn_mfma_f32_16x16x32_bf16(a0, b2, acc[0][2], 0, 0, 0);
        acc[0][3] = __builtin_amdgcn_mfma_f32_16x16x32_bf16(a0, b3, acc[0][3], 0, 0, 0);
        acc[1][0] = __builtin_amdgcn_mfma_f32_16x16x32_bf16(a1, b0, acc[1][0], 0, 0, 0);
        acc[1][1] = __builtin_amdgcn_mfma_f32_16x16x32_bf16(a1, b1, acc[1][1], 0, 0, 0);
        acc[1][2] = __builtin_amdgcn_mfma_f32_16x16x32_bf16(a1, b2, acc[1][2], 0, 0, 0);
        acc[1][3] = __builtin_amdgcn_mfma_f32_16x16x32_bf16(a1, b3, acc[1][3], 0, 0, 0);
        acc[2][0] = __builtin_amdgcn_mfma_f32_16x16x32_bf16(a2, b0, acc[2][0], 0, 0, 0);
        acc[2][1] = __builtin_amdgcn_mfma_f32_16x16x32_bf16(a2, b1, acc[2][1], 0, 0, 0);
        acc[2][2] = __builtin_amdgcn_mfma_f32_16x16x32_bf16(a2, b2, acc[2][2], 0, 0, 0);
        acc[2][3] = __builtin_amdgcn_mfma_f32_16x16x32_bf16(a2, b3, acc[2][3], 0, 0, 0);
        acc[3][0] = __builtin_amdgcn_mfma_f32_16x16x32_bf16(a3, b0, acc[3][0], 0, 0, 0);
        acc[3][1] = __builtin_amdgcn_mfma_f32_16x16x32_bf16(a3, b1, acc[3][1], 0, 0, 0);
        acc[3][2] = __builtin_amdgcn_mfma_f32_16x16x32_bf16(a3, b2, acc[3][2], 0, 0, 0);
        acc[3][3] = __builtin_amdgcn_mfma_f32_16x16x32_bf16(a3, b3, acc[3][3], 0, 0, 0);
    }

    #pragma unroll
    for (int jsub = 0; jsub < 4; ++jsub) {
        const int j = jb + jsub * 16 + row16;
        const float bb = bmr[j];
        #pragma unroll
        for (int nsub = 0; nsub < 4; ++nsub)
            #pragma unroll
            for (int r = 0; r < 4; ++r) {
                const int node = node0 + nsub * 16 + kg * 4 + r;
                float v = acc[nsub][jsub][r] + bb;
                v = v > 0.f ? v : 0.f;
                hn[(size_t)node * C2 + j] = f2bf(v);
            }
    }
}

// ---------------------------------------------------------------------------
// fc2: out[b][o][n] = relu( BN( sum_j W2[o][j]*hn[n][j] ) + x[b][o][n] )
// block: 256 thr = 4 waves (2x2), tile 128 o x 128 nodes   (D rows=o, cols=n)
// ---------------------------------------------------------------------------
__global__ __launch_bounds__(256) void fc2_mfma(
    const ushort* __restrict__ hn, const float* __restrict__ x,
    const ushort* __restrict__ W2bf, const float* __restrict__ b2,
    const float* __restrict__ g2, const float* __restrict__ be2,
    const float* __restrict__ m2, const float* __restrict__ v2,
    float* __restrict__ out)
{
    __shared__ float scS[Cc], shS[Cc];
    const int t = threadIdx.x;
    if (t < Cc) {
        const float s = g2[t] * rsqrtf(v2[t] + EPSf);
        scS[t] = s;
        shS[t] = (b2[t] - m2[t]) * s + be2[t];
    }
    __syncthreads();

    const int nt0 = blockIdx.x * 128;
    const int b  = nt0 >> 12;
    const int n0 = nt0 & 4095;
    const int w = t >> 6, lane = t & 63;
    const int row16 = lane & 15, kg = lane >> 4;
    const int wr = w >> 1, wc = w & 1;  // wr: o half, wc: node half

    f4_t acc[4][4];  // [osub][nsub]
    const f4_t zero = {0.f, 0.f, 0.f, 0.f};
    #pragma unroll
    for (int i = 0; i < 4; ++i)
        #pragma unroll
        for (int j = 0; j < 4; ++j) acc[i][j] = zero;

    #pragma unroll
    for (int ks = 0; ks < 8; ++ks) {
        const int k0 = ks * 32 + kg * 8;
        bf8_t aw[4];
        #pragma unroll
        for (int osub = 0; osub < 4; ++osub) {
            const int o = wr * 64 + osub * 16 + row16;
            aw[osub] = *(const bf8_t*)(W2bf + o * C2 + k0);
        }
        bf8_t bh[4];
        #pragma unroll
        for (int nsub = 0; nsub < 4; ++nsub) {
            const int node = nt0 + wc * 64 + nsub * 16 + row16;
            bh[nsub] = *(const bf8_t*)(hn + (size_t)node * C2 + k0);
        }
        #pragma unroll
        for (int osub = 0; osub < 4; ++osub)
            #pragma unroll
            for (int nsub = 0; nsub < 4; ++nsub)
                acc[osub][nsub] = __builtin_amdgcn_mfma_f32_16x16x32_bf16(
                    aw[osub], bh[nsub], acc[osub][nsub], 0, 0, 0);
    }

    #pragma unroll
    for (int osub = 0; osub < 4; ++osub)
        #pragma unroll
        for (int r = 0; r < 4; ++r) {
            const int o = wr * 64 + osub * 16 + kg * 4 + r;
            const float s = scS[o], sh = shS[o];
            const float* xr = x   + ((size_t)(b * Cc + o)) * Nn + n0 + wc * 64;
            float*       op = out + ((size_t)(b * Cc + o)) * Nn + n0 + wc * 64;
            #pragma unroll
            for (int nsub = 0; nsub < 4; ++nsub) {
                const int nn = nsub * 16 + row16;
                float v = acc[osub][nsub][r] * s + sh + xr[nn];
                v = v > 0.f ? v : 0.f;
                op[nn] = v;
            }
        }
}

// ---------------------------------------------------------------------------
extern "C" void kernel_launch(void* const* d_in, const int* in_sizes, int n_in,
                              void* d_out, int out_size, void* d_ws, size_t ws_size,
                              hipStream_t stream)
{
    const float* x   = (const float*)d_in[0];
    const int*   src = (const int*)  d_in[1];
    const float* W1  = (const float*)d_in[2];
    const float* b1  = (const float*)d_in[3];
    const float* g1  = (const float*)d_in[4];
    const float* be1 = (const float*)d_in[5];
    const float* m1  = (const float*)d_in[6];
    const float* v1  = (const float*)d_in[7];
    const float* Wmr = (const float*)d_in[8];
    const float* bmr = (const float*)d_in[9];
    const float* W2  = (const float*)d_in[10];
    const float* b2  = (const float*)d_in[11];
    const float* g2  = (const float*)d_in[12];
    const float* be2 = (const float*)d_in[13];
    const float* m2  = (const float*)d_in[14];
    const float* v2  = (const float*)d_in[15];
    float* out = (float*)d_out;

    ushort* W1bf  = (ushort*)d_ws;            // 16384
    ushort* Wmrbf = W1bf + 16384;             // 65536
    ushort* W2bf  = Wmrbf + 65536;            // 32768
    ushort* xn    = W2bf + 32768;             // 32768*128
    ushort* hn    = xn + (size_t)NODES * Cc;  // 32768*256

    prep_kernel<<<112, 256, 0, stream>>>(W1, Wmr, W2, W1bf, Wmrbf, W2bf);
    fc1_mfma<<<NODES / 128, 256, 0, stream>>>(x, W1bf, b1, g1, be1, m1, v1, xn);
    mr_mfma<<<NODES / 64, 256, 0, stream>>>(xn, src, Wmrbf, bmr, hn);
    fc2_mfma<<<NODES / 128, 256, 0, stream>>>(hn, x, W2bf, b2, g2, be2, m2, v2, out);
}

// Round 3
// 47.265 us; speedup vs baseline: 4.0644x; 1.2907x over previous
//
#include <hip/hip_runtime.h>

// Grapher block (DeepGCN MRConv) on MI355X — bf16 MFMA, mr+fc2 fused.
// fc1(Conv1d k=1)+BN+ReLU -> [gather/min/diff/cat -> FC(2Cx2C)+ReLU -> fc2+BN+res+ReLU] fused
// Scratch (d_ws): W1bf(32K) Wmrbf(128K) W2bf(64K), xn bf16 [32768][128] (8MB).
//
// MFMA 16x16x32 bf16 layout (guide §3, m89-verified):
//   A: row = lane&15, k = (lane>>4)*8 + j   (bf16x8 contiguous in k)
//   B: col = lane&15, k = (lane>>4)*8 + j
//   D: col = lane&15, row = (lane>>4)*4 + r

typedef short bf8_t __attribute__((ext_vector_type(8)));
typedef float f4_t  __attribute__((ext_vector_type(4)));

namespace {
constexpr int Bn = 8, Cc = 128, Nn = 4096, Kk = 16, C2 = 256;
constexpr int NODES = Bn * Nn;
constexpr float EPSf = 1e-5f;
}

__device__ __forceinline__ unsigned short f2bf(float f) {
    unsigned u = __float_as_uint(f);
    u += 0x7fffu + ((u >> 16) & 1u);   // RNE; NaN impossible in our data path
    return (unsigned short)(u >> 16);
}
__device__ __forceinline__ float bflo(unsigned u) { return __uint_as_float(u << 16); }
__device__ __forceinline__ float bfhi(unsigned u) { return __uint_as_float(u & 0xffff0000u); }
__device__ __forceinline__ unsigned diff2(unsigned o, unsigned m) {
    const float lo = bflo(o) - bflo(m);
    const float hi = bfhi(o) - bfhi(m);
    return (unsigned)f2bf(lo) | ((unsigned)f2bf(hi) << 16);
}

// packed u16 min: valid as bf16-min because all gathered values are >= 0 (post-ReLU)
#define PKMIN(a, b) asm("v_pk_min_u16 %0, %0, %1" : "+v"(a) : "v"(b))

// ---------------------------------------------------------------------------
// prep: convert W1 / Wmr / W2 fp32 -> bf16 row-major (one-time per launch)
// ---------------------------------------------------------------------------
__global__ __launch_bounds__(256) void prep_kernel(
    const float* __restrict__ W1, const float* __restrict__ Wmr,
    const float* __restrict__ W2, ushort* __restrict__ W1bf,
    ushort* __restrict__ Wmrbf, ushort* __restrict__ W2bf)
{
    const int e = (blockIdx.x * 256 + threadIdx.x) * 4;  // 114688 elems total
    const float* s;
    ushort* d;
    if (e < 16384)      { s = W1 + e;          d = W1bf + e; }
    else if (e < 81920) { s = Wmr + (e-16384); d = Wmrbf + (e-16384); }
    else                { s = W2 + (e-81920);  d = W2bf + (e-81920); }
    const float4 v = *(const float4*)s;
    ushort4 r;
    r.x = f2bf(v.x); r.y = f2bf(v.y); r.z = f2bf(v.z); r.w = f2bf(v.w);
    *(ushort4*)d = r;
}

// ---------------------------------------------------------------------------
// fc1: xn[n][o] = relu( BN( sum_c W1[o][c]*x[b][c][n] ) )   (D rows=n, cols=o)
// block: 256 thr = 4 waves (2x2), tile 128 nodes x 128 o
// ---------------------------------------------------------------------------
__global__ __launch_bounds__(256) void fc1_mfma(
    const float* __restrict__ x, const ushort* __restrict__ W1bf,
    const float* __restrict__ b1, const float* __restrict__ g1,
    const float* __restrict__ be1, const float* __restrict__ m1,
    const float* __restrict__ v1, ushort* __restrict__ xn)
{
    __shared__ float scS[Cc], shS[Cc];
    const int t = threadIdx.x;
    if (t < Cc) {
        const float s = g1[t] * rsqrtf(v1[t] + EPSf);
        scS[t] = s;
        shS[t] = (b1[t] - m1[t]) * s + be1[t];
    }
    __syncthreads();

    const int nt0 = blockIdx.x * 128;
    const int b  = nt0 >> 12;
    const int n0 = nt0 & 4095;
    const int w = t >> 6, lane = t & 63;
    const int row16 = lane & 15, kg = lane >> 4;
    const int wr = w >> 1, wc = w & 1;   // wr: node half, wc: o half
    const float* xb = x + (size_t)b * Cc * Nn;

    f4_t acc[4][4];  // [nsub][osub]
    const f4_t zero = {0.f, 0.f, 0.f, 0.f};
    #pragma unroll
    for (int i = 0; i < 4; ++i)
        #pragma unroll
        for (int j = 0; j < 4; ++j) acc[i][j] = zero;

    #pragma unroll
    for (int ks = 0; ks < 4; ++ks) {
        const int c0 = ks * 32 + kg * 8;
        bf8_t af[4];
        #pragma unroll
        for (int nsub = 0; nsub < 4; ++nsub) {
            const float* xp = xb + (size_t)c0 * Nn + (n0 + wr * 64 + nsub * 16 + row16);
            bf8_t a;
            #pragma unroll
            for (int j = 0; j < 8; ++j) a[j] = (short)f2bf(xp[(size_t)j * Nn]);
            af[nsub] = a;
        }
        bf8_t bw[4];
        #pragma unroll
        for (int osub = 0; osub < 4; ++osub) {
            const int o = wc * 64 + osub * 16 + row16;
            bw[osub] = *(const bf8_t*)(W1bf + o * Cc + c0);
        }
        #pragma unroll
        for (int nsub = 0; nsub < 4; ++nsub)
            #pragma unroll
            for (int osub = 0; osub < 4; ++osub)
                acc[nsub][osub] = __builtin_amdgcn_mfma_f32_16x16x32_bf16(
                    af[nsub], bw[osub], acc[nsub][osub], 0, 0, 0);
    }

    #pragma unroll
    for (int osub = 0; osub < 4; ++osub) {
        const int o = wc * 64 + osub * 16 + row16;
        const float s = scS[o], sh = shS[o];
        #pragma unroll
        for (int nsub = 0; nsub < 4; ++nsub)
            #pragma unroll
            for (int r = 0; r < 4; ++r) {
                const int node = nt0 + wr * 64 + nsub * 16 + kg * 4 + r;
                float v = acc[nsub][osub][r] * s + sh;
                v = v > 0.f ? v : 0.f;
                xn[(size_t)node * Cc + o] = f2bf(v);
            }
    }
}

// ---------------------------------------------------------------------------
// fused mr+fc2 per 64-node tile:
//   P1: cat = [xn | xn - min_k xn[src]]           -> catS (LDS)
//   P2: hn  = relu(cat @ Wmr^T + bmr)  (A=Wmr, B=cat; D rows=j -> packed LDS
//       writeback into catS, reusing the buffer)
//   P3: out = relu( BN(W2 @ hn) + x )  (A=W2, B=hn(catS); D rows=o)
// Block = 256 thr = 4 waves; wave w owns j-band 64w (P2), o-band 32w (P3).
// XCD swizzle: blocks with bid%8==c process batch c -> gather hits XCD-local L2.
// ---------------------------------------------------------------------------
__global__ __launch_bounds__(256) void mrfc2_mfma(
    const ushort* __restrict__ xn, const int* __restrict__ src,
    const ushort* __restrict__ Wmrbf, const float* __restrict__ bmr,
    const ushort* __restrict__ W2bf, const float* __restrict__ x,
    const float* __restrict__ b2, const float* __restrict__ g2,
    const float* __restrict__ be2, const float* __restrict__ m2,
    const float* __restrict__ v2, float* __restrict__ out)
{
    __shared__ __align__(16) ushort catS[64 * 264];  // [node][256] pad->264
    __shared__ int srcS[64 * Kk];
    __shared__ float scS[Cc], shS[Cc];
    const int t = threadIdx.x;
    const int bid = blockIdx.x;
    const int lb = (bid & 7) * 64 + (bid >> 3);      // XCD-local batch mapping
    const int node0 = lb * 64;
    const int b  = node0 >> 12;
    const int n0 = node0 & 4095;

    if (t < Cc) {
        const float s = g2[t] * rsqrtf(v2[t] + EPSf);
        scS[t] = s;
        shS[t] = (b2[t] - m2[t]) * s + be2[t];
    }
    ((int4*)srcS)[t] = ((const int4*)(src + (size_t)node0 * Kk))[t];
    __syncthreads();

    {   // P1: gather + u16-min + diff; 4 threads/node, 32 channels each
        const int nl = t >> 2, q = t & 3;
        const ushort* orow = xn + (size_t)(node0 + nl) * Cc + q * 32;
        uint4 ow0 = *(const uint4*)(orow +  0);
        uint4 ow1 = *(const uint4*)(orow +  8);
        uint4 ow2 = *(const uint4*)(orow + 16);
        uint4 ow3 = *(const uint4*)(orow + 24);
        const int* sl = srcS + nl * Kk;
        const ushort* sr = xn + (size_t)sl[0] * Cc + q * 32;
        uint4 mn0 = *(const uint4*)(sr +  0);
        uint4 mn1 = *(const uint4*)(sr +  8);
        uint4 mn2 = *(const uint4*)(sr + 16);
        uint4 mn3 = *(const uint4*)(sr + 24);
        #pragma unroll
        for (int k = 1; k < Kk; ++k) {
            const ushort* s = xn + (size_t)sl[k] * Cc + q * 32;
            uint4 v0 = *(const uint4*)(s +  0);
            uint4 v1 = *(const uint4*)(s +  8);
            uint4 v2_ = *(const uint4*)(s + 16);
            uint4 v3 = *(const uint4*)(s + 24);
            PKMIN(mn0.x, v0.x); PKMIN(mn0.y, v0.y); PKMIN(mn0.z, v0.z); PKMIN(mn0.w, v0.w);
            PKMIN(mn1.x, v1.x); PKMIN(mn1.y, v1.y); PKMIN(mn1.z, v1.z); PKMIN(mn1.w, v1.w);
            PKMIN(mn2.x, v2_.x); PKMIN(mn2.y, v2_.y); PKMIN(mn2.z, v2_.z); PKMIN(mn2.w, v2_.w);
            PKMIN(mn3.x, v3.x); PKMIN(mn3.y, v3.y); PKMIN(mn3.z, v3.z); PKMIN(mn3.w, v3.w);
        }
        unsigned* crow = (unsigned*)(catS + nl * 264);
        *(uint4*)(crow + q * 16 +  0) = ow0;
        *(uint4*)(crow + q * 16 +  4) = ow1;
        *(uint4*)(crow + q * 16 +  8) = ow2;
        *(uint4*)(crow + q * 16 + 12) = ow3;
        uint4 d0, d1, d2, d3;
        d0.x = diff2(ow0.x, mn0.x); d0.y = diff2(ow0.y, mn0.y); d0.z = diff2(ow0.z, mn0.z); d0.w = diff2(ow0.w, mn0.w);
        d1.x = diff2(ow1.x, mn1.x); d1.y = diff2(ow1.y, mn1.y); d1.z = diff2(ow1.z, mn1.z); d1.w = diff2(ow1.w, mn1.w);
        d2.x = diff2(ow2.x, mn2.x); d2.y = diff2(ow2.y, mn2.y); d2.z = diff2(ow2.z, mn2.z); d2.w = diff2(ow2.w, mn2.w);
        d3.x = diff2(ow3.x, mn3.x); d3.y = diff2(ow3.y, mn3.y); d3.z = diff2(ow3.z, mn3.z); d3.w = diff2(ow3.w, mn3.w);
        *(uint4*)(crow + 64 + q * 16 +  0) = d0;
        *(uint4*)(crow + 64 + q * 16 +  4) = d1;
        *(uint4*)(crow + 64 + q * 16 +  8) = d2;
        *(uint4*)(crow + 64 + q * 16 + 12) = d3;
    }
    __syncthreads();

    const int w = t >> 6, lane = t & 63;
    const int row16 = lane & 15, kg = lane >> 4;

    // ---- P2: hn-band = relu(Wmr[jb:jb+64] @ cat^T + bmr)  (D: row=j, col=node)
    const int jb = w * 64;
    {
        f4_t acc[4][4];  // [jsub][nsub]
        const f4_t zero = {0.f, 0.f, 0.f, 0.f};
        #pragma unroll
        for (int i = 0; i < 4; ++i)
            #pragma unroll
            for (int j = 0; j < 4; ++j) acc[i][j] = zero;

        #pragma unroll
        for (int ks = 0; ks < 8; ++ks) {
            const int k0 = ks * 32 + kg * 8;
            bf8_t aw[4], bc[4];
            #pragma unroll
            for (int jsub = 0; jsub < 4; ++jsub)
                aw[jsub] = *(const bf8_t*)(Wmrbf + (size_t)(jb + jsub * 16 + row16) * C2 + k0);
            #pragma unroll
            for (int nsub = 0; nsub < 4; ++nsub)
                bc[nsub] = *(const bf8_t*)(catS + (nsub * 16 + row16) * 264 + k0);
            #pragma unroll
            for (int jsub = 0; jsub < 4; ++jsub)
                #pragma unroll
                for (int nsub = 0; nsub < 4; ++nsub)
                    acc[jsub][nsub] = __builtin_amdgcn_mfma_f32_16x16x32_bf16(
                        aw[jsub], bc[nsub], acc[jsub][nsub], 0, 0, 0);
        }
        __syncthreads();  // all P2 reads of catS complete

        // writeback hn into catS: lane's 4 rows are consecutive j -> uint2 per frag
        #pragma unroll
        for (int jsub = 0; jsub < 4; ++jsub) {
            const float4 bb = *(const float4*)(bmr + jb + jsub * 16 + kg * 4);
            #pragma unroll
            for (int nsub = 0; nsub < 4; ++nsub) {
                float v0 = acc[jsub][nsub][0] + bb.x;
                float v1 = acc[jsub][nsub][1] + bb.y;
                float v2_ = acc[jsub][nsub][2] + bb.z;
                float v3 = acc[jsub][nsub][3] + bb.w;
                v0 = v0 > 0.f ? v0 : 0.f;
                v1 = v1 > 0.f ? v1 : 0.f;
                v2_ = v2_ > 0.f ? v2_ : 0.f;
                v3 = v3 > 0.f ? v3 : 0.f;
                uint2 pk;
                pk.x = (unsigned)f2bf(v0) | ((unsigned)f2bf(v1) << 16);
                pk.y = (unsigned)f2bf(v2_) | ((unsigned)f2bf(v3) << 16);
                *(uint2*)(catS + (nsub * 16 + row16) * 264 + jb + jsub * 16 + kg * 4) = pk;
            }
        }
    }
    __syncthreads();

    // ---- P3: out-band = relu(BN(W2[ob:ob+32] @ hn^T) + x)  (D: row=o, col=node)
    {
        const int ob = w * 32;
        f4_t acc[2][4];  // [osub][nsub]
        const f4_t zero = {0.f, 0.f, 0.f, 0.f};
        #pragma unroll
        for (int i = 0; i < 2; ++i)
            #pragma unroll
            for (int j = 0; j < 4; ++j) acc[i][j] = zero;

        #pragma unroll
        for (int ks = 0; ks < 8; ++ks) {
            const int k0 = ks * 32 + kg * 8;
            bf8_t aw[2], bh[4];
            #pragma unroll
            for (int osub = 0; osub < 2; ++osub)
                aw[osub] = *(const bf8_t*)(W2bf + (size_t)(ob + osub * 16 + row16) * C2 + k0);
            #pragma unroll
            for (int nsub = 0; nsub < 4; ++nsub)
                bh[nsub] = *(const bf8_t*)(catS + (nsub * 16 + row16) * 264 + k0);
            #pragma unroll
            for (int osub = 0; osub < 2; ++osub)
                #pragma unroll
                for (int nsub = 0; nsub < 4; ++nsub)
                    acc[osub][nsub] = __builtin_amdgcn_mfma_f32_16x16x32_bf16(
                        aw[osub], bh[nsub], acc[osub][nsub], 0, 0, 0);
        }

        #pragma unroll
        for (int osub = 0; osub < 2; ++osub)
            #pragma unroll
            for (int r = 0; r < 4; ++r) {
                const int o = ob + osub * 16 + kg * 4 + r;
                const float s = scS[o], sh = shS[o];
                const float* xr = x   + ((size_t)(b * Cc + o)) * Nn + n0;
                float*       op = out + ((size_t)(b * Cc + o)) * Nn + n0;
                #pragma unroll
                for (int nsub = 0; nsub < 4; ++nsub) {
                    const int nn = nsub * 16 + row16;
                    float v = acc[osub][nsub][r] * s + sh + xr[nn];
                    v = v > 0.f ? v : 0.f;
                    op[nn] = v;
                }
            }
    }
}

// ---------------------------------------------------------------------------
extern "C" void kernel_launch(void* const* d_in, const int* in_sizes, int n_in,
                              void* d_out, int out_size, void* d_ws, size_t ws_size,
                              hipStream_t stream)
{
    const float* x   = (const float*)d_in[0];
    const int*   src = (const int*)  d_in[1];
    const float* W1  = (const float*)d_in[2];
    const float* b1  = (const float*)d_in[3];
    const float* g1  = (const float*)d_in[4];
    const float* be1 = (const float*)d_in[5];
    const float* m1  = (const float*)d_in[6];
    const float* v1  = (const float*)d_in[7];
    const float* Wmr = (const float*)d_in[8];
    const float* bmr = (const float*)d_in[9];
    const float* W2  = (const float*)d_in[10];
    const float* b2  = (const float*)d_in[11];
    const float* g2  = (const float*)d_in[12];
    const float* be2 = (const float*)d_in[13];
    const float* m2  = (const float*)d_in[14];
    const float* v2  = (const float*)d_in[15];
    float* out = (float*)d_out;

    ushort* W1bf  = (ushort*)d_ws;            // 16384
    ushort* Wmrbf = W1bf + 16384;             // 65536
    ushort* W2bf  = Wmrbf + 65536;            // 32768
    ushort* xn    = W2bf + 32768;             // 32768*128

    prep_kernel<<<112, 256, 0, stream>>>(W1, Wmr, W2, W1bf, Wmrbf, W2bf);
    fc1_mfma<<<NODES / 128, 256, 0, stream>>>(x, W1bf, b1, g1, be1, m1, v1, xn);
    mrfc2_mfma<<<NODES / 64, 256, 0, stream>>>(xn, src, Wmrbf, bmr, W2bf, x,
                                               b2, g2, be2, m2, v2, out);
}

// Round 5
// 42.449 us; speedup vs baseline: 4.5256x; 1.1135x over previous
//
#include <hip/hip_runtime.h>

// Grapher block (DeepGCN MRConv) on MI355X — bf16 MFMA, occupancy-tuned.
// prep(W->bf16) -> fc1 (LDS-transposed x, 512thr) -> fused mr+fc2 (512thr).
// Scratch (d_ws): W1bf(32K) Wmrbf(128K) W2bf(64K), xn bf16 [32768][128] (8MB).
//
// MFMA 16x16x32 bf16 layout (guide §3, m89-verified):
//   A: row = lane&15, k = (lane>>4)*8 + j   (bf16x8 contiguous in k)
//   B: col = lane&15, k = (lane>>4)*8 + j
//   D: col = lane&15, row = (lane>>4)*4 + r

typedef short bf8_t __attribute__((ext_vector_type(8)));
typedef float f4_t  __attribute__((ext_vector_type(4)));

namespace {
constexpr int Bn = 8, Cc = 128, Nn = 4096, Kk = 16, C2 = 256;
constexpr int NODES = Bn * Nn;
constexpr float EPSf = 1e-5f;
}

__device__ __forceinline__ unsigned short f2bf(float f) {
    unsigned u = __float_as_uint(f);
    u += 0x7fffu + ((u >> 16) & 1u);   // RNE
    return (unsigned short)(u >> 16);
}
__device__ __forceinline__ unsigned pk2(float a, float b) {
    return (unsigned)f2bf(a) | ((unsigned)f2bf(b) << 16);
}
__device__ __forceinline__ float bflo(unsigned u) { return __uint_as_float(u << 16); }
__device__ __forceinline__ float bfhi(unsigned u) { return __uint_as_float(u & 0xffff0000u); }
__device__ __forceinline__ unsigned diff2(unsigned o, unsigned m) {
    return pk2(bflo(o) - bflo(m), bfhi(o) - bfhi(m));
}

// packed u16 min: valid as bf16-min because all values are >= 0 (post-ReLU)
#define PKMIN(a, b) asm("v_pk_min_u16 %0, %0, %1" : "+v"(a) : "v"(b))

// ---------------------------------------------------------------------------
// prep: convert W1 / Wmr / W2 fp32 -> bf16 row-major (one-time per launch)
// ---------------------------------------------------------------------------
__global__ __launch_bounds__(256) void prep_kernel(
    const float* __restrict__ W1, const float* __restrict__ Wmr,
    const float* __restrict__ W2, ushort* __restrict__ W1bf,
    ushort* __restrict__ Wmrbf, ushort* __restrict__ W2bf)
{
    const int e = (blockIdx.x * 256 + threadIdx.x) * 4;  // 114688 elems total
    const float* s;
    ushort* d;
    if (e < 16384)      { s = W1 + e;          d = W1bf + e; }
    else if (e < 81920) { s = Wmr + (e-16384); d = Wmrbf + (e-16384); }
    else                { s = W2 + (e-81920);  d = W2bf + (e-81920); }
    const float4 v = *(const float4*)s;
    uint2 r;
    r.x = pk2(v.x, v.y);
    r.y = pk2(v.z, v.w);
    *(uint2*)d = r;
}

// ---------------------------------------------------------------------------
// fc1: xn[n][o] = relu( BN( sum_c W1[o][c]*x[b][c][n] ) )   (D rows=n, cols=o)
// block: 512 thr = 8 waves (2 node-halves x 4 o-bands), tile 64 nodes x 128 o
// x tile transposed+converted into LDS: [64 node][128 c] bf16, row pad 136 u16.
// ---------------------------------------------------------------------------
__global__ __launch_bounds__(512) void fc1_mfma(
    const float* __restrict__ x, const ushort* __restrict__ W1bf,
    const float* __restrict__ b1, const float* __restrict__ g1,
    const float* __restrict__ be1, const float* __restrict__ m1,
    const float* __restrict__ v1, ushort* __restrict__ xn)
{
    __shared__ __align__(16) ushort xS[64 * 136];   // 17.4 KB
    __shared__ float scS[Cc], shS[Cc];
    const int t = threadIdx.x;
    if (t < Cc) {
        const float s = g1[t] * rsqrtf(v1[t] + EPSf);
        scS[t] = s;
        shS[t] = (b1[t] - m1[t]) * s + be1[t];
    }

    const int nt0 = blockIdx.x * 64;
    const int b  = nt0 >> 12;
    const int n0 = nt0 & 4095;

    // stage + transpose + convert: thread tile = 4 nodes x 4 channels
    {
        const int cg = t & 31, ng = t >> 5;          // c0 = cg*4, nodes ng*4..+3
        const float* xp = x + ((size_t)(b * Cc + cg * 4)) * Nn + n0 + ng * 4;
        const float4 r0 = *(const float4*)(xp + 0 * (size_t)Nn);
        const float4 r1 = *(const float4*)(xp + 1 * (size_t)Nn);
        const float4 r2 = *(const float4*)(xp + 2 * (size_t)Nn);
        const float4 r3 = *(const float4*)(xp + 3 * (size_t)Nn);
        const float c0n[4] = {r0.x, r0.y, r0.z, r0.w};
        const float c1n[4] = {r1.x, r1.y, r1.z, r1.w};
        const float c2n[4] = {r2.x, r2.y, r2.z, r2.w};
        const float c3n[4] = {r3.x, r3.y, r3.z, r3.w};
        #pragma unroll
        for (int i = 0; i < 4; ++i) {
            uint2 pk;
            pk.x = pk2(c0n[i], c1n[i]);
            pk.y = pk2(c2n[i], c3n[i]);
            *(uint2*)(xS + (ng * 4 + i) * 136 + cg * 4) = pk;
        }
    }
    __syncthreads();

    const int w = t >> 6, lane = t & 63;
    const int row16 = lane & 15, kg = lane >> 4;
    const int wr = w >> 2, wc = w & 3;   // wr: 32-node half, wc: 32-o band

    f4_t acc[2][2];  // [nsub][osub]
    const f4_t zero = {0.f, 0.f, 0.f, 0.f};
    #pragma unroll
    for (int i = 0; i < 2; ++i)
        #pragma unroll
        for (int j = 0; j < 2; ++j) acc[i][j] = zero;

    #pragma unroll
    for (int ks = 0; ks < 4; ++ks) {
        const int k0 = ks * 32 + kg * 8;
        bf8_t af[2], bw[2];
        #pragma unroll
        for (int nsub = 0; nsub < 2; ++nsub)
            af[nsub] = *(const bf8_t*)(xS + (wr * 32 + nsub * 16 + row16) * 136 + k0);
        #pragma unroll
        for (int osub = 0; osub < 2; ++osub)
            bw[osub] = *(const bf8_t*)(W1bf + (wc * 32 + osub * 16 + row16) * Cc + k0);
        #pragma unroll
        for (int nsub = 0; nsub < 2; ++nsub)
            #pragma unroll
            for (int osub = 0; osub < 2; ++osub)
                acc[nsub][osub] = __builtin_amdgcn_mfma_f32_16x16x32_bf16(
                    af[nsub], bw[osub], acc[nsub][osub], 0, 0, 0);
    }

    #pragma unroll
    for (int osub = 0; osub < 2; ++osub) {
        const int o = wc * 32 + osub * 16 + row16;
        const float s = scS[o], sh = shS[o];
        #pragma unroll
        for (int nsub = 0; nsub < 2; ++nsub)
            #pragma unroll
            for (int r = 0; r < 4; ++r) {
                const int node = nt0 + wr * 32 + nsub * 16 + kg * 4 + r;
                float v = acc[nsub][osub][r] * s + sh;
                v = v > 0.f ? v : 0.f;
                xn[(size_t)node * Cc + o] = f2bf(v);
            }
    }
}

// ---------------------------------------------------------------------------
// fused mr+fc2 per 64-node tile, 512 thr = 8 waves:
//   P1: cat = [xn | xn - min_k xn[src]]  -> catS (8 thr/node, 16-ch slices)
//   P2: hn  = relu(Wmr @ cat^T + bmr)    wave j-band 32; packed writeback->catS
//   P3: out = relu( BN(W2 @ hn^T) + x )  wave o-band 16
// XCD swizzle: bid%8 -> batch, so gathers hit XCD-local L2.
// ---------------------------------------------------------------------------
__global__ __launch_bounds__(512) void mrfc2_mfma(
    const ushort* __restrict__ xn, const int* __restrict__ src,
    const ushort* __restrict__ Wmrbf, const float* __restrict__ bmr,
    const ushort* __restrict__ W2bf, const float* __restrict__ x,
    const float* __restrict__ b2, const float* __restrict__ g2,
    const float* __restrict__ be2, const float* __restrict__ m2,
    const float* __restrict__ v2, float* __restrict__ out)
{
    __shared__ __align__(16) ushort catS[64 * 264];  // [node][256] pad->264
    __shared__ int srcS[64 * Kk];
    __shared__ float scS[Cc], shS[Cc];
    const int t = threadIdx.x;
    const int bid = blockIdx.x;
    const int lb = (bid & 7) * 64 + (bid >> 3);      // XCD-local batch mapping
    const int node0 = lb * 64;
    const int b  = node0 >> 12;
    const int n0 = node0 & 4095;

    if (t < Cc) {
        const float s = g2[t] * rsqrtf(v2[t] + EPSf);
        scS[t] = s;
        shS[t] = (b2[t] - m2[t]) * s + be2[t];
    }
    if (t < 256)
        ((int4*)srcS)[t] = ((const int4*)(src + (size_t)node0 * Kk))[t];
    __syncthreads();

    {   // P1: gather + u16-min + diff; 8 threads/node, 16 channels each
        const int nl = t >> 3, q = t & 7;
        const ushort* orow = xn + (size_t)(node0 + nl) * Cc + q * 16;
        uint4 ow0 = *(const uint4*)(orow + 0);
        uint4 ow1 = *(const uint4*)(orow + 8);
        const int* sl = srcS + nl * Kk;
        const ushort* sr = xn + (size_t)sl[0] * Cc + q * 16;
        uint4 mn0 = *(const uint4*)(sr + 0);
        uint4 mn1 = *(const uint4*)(sr + 8);
        #pragma unroll
        for (int k = 1; k < Kk; ++k) {
            const ushort* s = xn + (size_t)sl[k] * Cc + q * 16;
            uint4 v0 = *(const uint4*)(s + 0);
            uint4 v1 = *(const uint4*)(s + 8);
            PKMIN(mn0.x, v0.x); PKMIN(mn0.y, v0.y); PKMIN(mn0.z, v0.z); PKMIN(mn0.w, v0.w);
            PKMIN(mn1.x, v1.x); PKMIN(mn1.y, v1.y); PKMIN(mn1.z, v1.z); PKMIN(mn1.w, v1.w);
        }
        unsigned* crow = (unsigned*)(catS + nl * 264);
        *(uint4*)(crow + q * 8 + 0) = ow0;
        *(uint4*)(crow + q * 8 + 4) = ow1;
        uint4 d0, d1;
        d0.x = diff2(ow0.x, mn0.x); d0.y = diff2(ow0.y, mn0.y);
        d0.z = diff2(ow0.z, mn0.z); d0.w = diff2(ow0.w, mn0.w);
        d1.x = diff2(ow1.x, mn1.x); d1.y = diff2(ow1.y, mn1.y);
        d1.z = diff2(ow1.z, mn1.z); d1.w = diff2(ow1.w, mn1.w);
        *(uint4*)(crow + 64 + q * 8 + 0) = d0;
        *(uint4*)(crow + 64 + q * 8 + 4) = d1;
    }
    __syncthreads();

    const int w = t >> 6, lane = t & 63;
    const int row16 = lane & 15, kg = lane >> 4;

    // ---- P2: hn j-band = relu(Wmr[jb:jb+32] @ cat^T + bmr)  (D: row=j, col=node)
    const int jb = w * 32;
    {
        f4_t acc[2][4];  // [jsub][nsub]
        const f4_t zero = {0.f, 0.f, 0.f, 0.f};
        #pragma unroll
        for (int i = 0; i < 2; ++i)
            #pragma unroll
            for (int j = 0; j < 4; ++j) acc[i][j] = zero;

        #pragma unroll
        for (int ks = 0; ks < 8; ++ks) {
            const int k0 = ks * 32 + kg * 8;
            bf8_t aw[2], bc[4];
            #pragma unroll
            for (int jsub = 0; jsub < 2; ++jsub)
                aw[jsub] = *(const bf8_t*)(Wmrbf + (size_t)(jb + jsub * 16 + row16) * C2 + k0);
            #pragma unroll
            for (int nsub = 0; nsub < 4; ++nsub)
                bc[nsub] = *(const bf8_t*)(catS + (nsub * 16 + row16) * 264 + k0);
            #pragma unroll
            for (int jsub = 0; jsub < 2; ++jsub)
                #pragma unroll
                for (int nsub = 0; nsub < 4; ++nsub)
                    acc[jsub][nsub] = __builtin_amdgcn_mfma_f32_16x16x32_bf16(
                        aw[jsub], bc[nsub], acc[jsub][nsub], 0, 0, 0);
        }
        __syncthreads();  // all P2 reads of catS complete

        // writeback hn into catS: lane's 4 acc rows are consecutive j -> uint2
        #pragma unroll
        for (int jsub = 0; jsub < 2; ++jsub) {
            const float4 bb = *(const float4*)(bmr + jb + jsub * 16 + kg * 4);
            #pragma unroll
            for (int nsub = 0; nsub < 4; ++nsub) {
                float v0 = acc[jsub][nsub][0] + bb.x;
                float v1 = acc[jsub][nsub][1] + bb.y;
                float v2_ = acc[jsub][nsub][2] + bb.z;
                float v3 = acc[jsub][nsub][3] + bb.w;
                v0 = v0 > 0.f ? v0 : 0.f;
                v1 = v1 > 0.f ? v1 : 0.f;
                v2_ = v2_ > 0.f ? v2_ : 0.f;
                v3 = v3 > 0.f ? v3 : 0.f;
                uint2 pk;
                pk.x = pk2(v0, v1);
                pk.y = pk2(v2_, v3);
                *(uint2*)(catS + (nsub * 16 + row16) * 264 + jb + jsub * 16 + kg * 4) = pk;
            }
        }
    }
    __syncthreads();

    // ---- P3: out o-band = relu(BN(W2[ob:ob+16] @ hn^T) + x)  (D: row=o, col=node)
    {
        const int ob = w * 16;
        f4_t acc[4];  // [nsub]
        const f4_t zero = {0.f, 0.f, 0.f, 0.f};
        #pragma unroll
        for (int j = 0; j < 4; ++j) acc[j] = zero;

        #pragma unroll
        for (int ks = 0; ks < 8; ++ks) {
            const int k0 = ks * 32 + kg * 8;
            const bf8_t aw = *(const bf8_t*)(W2bf + (size_t)(ob + row16) * C2 + k0);
            #pragma unroll
            for (int nsub = 0; nsub < 4; ++nsub) {
                const bf8_t bh = *(const bf8_t*)(catS + (nsub * 16 + row16) * 264 + k0);
                acc[nsub] = __builtin_amdgcn_mfma_f32_16x16x32_bf16(aw, bh, acc[nsub], 0, 0, 0);
            }
        }

        #pragma unroll
        for (int r = 0; r < 4; ++r) {
            const int o = ob + kg * 4 + r;
            const float s = scS[o], sh = shS[o];
            const float* xr = x   + ((size_t)(b * Cc + o)) * Nn + n0;
            float*       op = out + ((size_t)(b * Cc + o)) * Nn + n0;
            #pragma unroll
            for (int nsub = 0; nsub < 4; ++nsub) {
                const int nn = nsub * 16 + row16;
                float v = acc[nsub][r] * s + sh + xr[nn];
                v = v > 0.f ? v : 0.f;
                op[nn] = v;
            }
        }
    }
}

// ---------------------------------------------------------------------------
extern "C" void kernel_launch(void* const* d_in, const int* in_sizes, int n_in,
                              void* d_out, int out_size, void* d_ws, size_t ws_size,
                              hipStream_t stream)
{
    const float* x   = (const float*)d_in[0];
    const int*   src = (const int*)  d_in[1];
    const float* W1  = (const float*)d_in[2];
    const float* b1  = (const float*)d_in[3];
    const float* g1  = (const float*)d_in[4];
    const float* be1 = (const float*)d_in[5];
    const float* m1  = (const float*)d_in[6];
    const float* v1  = (const float*)d_in[7];
    const float* Wmr = (const float*)d_in[8];
    const float* bmr = (const float*)d_in[9];
    const float* W2  = (const float*)d_in[10];
    const float* b2  = (const float*)d_in[11];
    const float* g2  = (const float*)d_in[12];
    const float* be2 = (const float*)d_in[13];
    const float* m2  = (const float*)d_in[14];
    const float* v2  = (const float*)d_in[15];
    float* out = (float*)d_out;

    ushort* W1bf  = (ushort*)d_ws;            // 16384
    ushort* Wmrbf = W1bf + 16384;             // 65536
    ushort* W2bf  = Wmrbf + 65536;            // 32768
    ushort* xn    = W2bf + 32768;             // 32768*128

    prep_kernel<<<112, 256, 0, stream>>>(W1, Wmr, W2, W1bf, Wmrbf, W2bf);
    fc1_mfma<<<NODES / 64, 512, 0, stream>>>(x, W1bf, b1, g1, be1, m1, v1, xn);
    mrfc2_mfma<<<NODES / 64, 512, 0, stream>>>(xn, src, Wmrbf, bmr, W2bf, x,
                                               b2, g2, be2, m2, v2, out);
}

// Round 6
// 39.515 us; speedup vs baseline: 4.8616x; 1.0742x over previous
//
#include <hip/hip_runtime.h>

// Grapher block (DeepGCN MRConv) on MI355X — bf16 MFMA, coalesced fc1.
// prep(W->bf16) -> fc1 (coalesced+XOR-swizzled LDS transpose) -> fused mr+fc2.
// Scratch (d_ws): W1bf(32K) Wmrbf(128K) W2bf(64K), xn bf16 [32768][128] (8MB).
//
// MFMA 16x16x32 bf16 layout (guide §3, m89-verified):
//   A: row = lane&15, k = (lane>>4)*8 + j   (bf16x8 contiguous in k)
//   B: col = lane&15, k = (lane>>4)*8 + j
//   D: col = lane&15, row = (lane>>4)*4 + r

typedef short bf8_t __attribute__((ext_vector_type(8)));
typedef float f4_t  __attribute__((ext_vector_type(4)));

namespace {
constexpr int Bn = 8, Cc = 128, Nn = 4096, Kk = 16, C2 = 256;
constexpr int NODES = Bn * Nn;
constexpr float EPSf = 1e-5f;
}

__device__ __forceinline__ unsigned short f2bf(float f) {
    unsigned u = __float_as_uint(f);
    u += 0x7fffu + ((u >> 16) & 1u);   // RNE
    return (unsigned short)(u >> 16);
}
__device__ __forceinline__ unsigned pk2(float a, float b) {
    return (unsigned)f2bf(a) | ((unsigned)f2bf(b) << 16);
}
__device__ __forceinline__ float bflo(unsigned u) { return __uint_as_float(u << 16); }
__device__ __forceinline__ float bfhi(unsigned u) { return __uint_as_float(u & 0xffff0000u); }
__device__ __forceinline__ unsigned diff2(unsigned o, unsigned m) {
    return pk2(bflo(o) - bflo(m), bfhi(o) - bfhi(m));
}

// packed u16 min: valid as bf16-min because all values are >= 0 (post-ReLU)
#define PKMIN(a, b) asm("v_pk_min_u16 %0, %0, %1" : "+v"(a) : "v"(b))

// ---------------------------------------------------------------------------
// prep: convert W1 / Wmr / W2 fp32 -> bf16 row-major (one-time per launch)
// ---------------------------------------------------------------------------
__global__ __launch_bounds__(256) void prep_kernel(
    const float* __restrict__ W1, const float* __restrict__ Wmr,
    const float* __restrict__ W2, ushort* __restrict__ W1bf,
    ushort* __restrict__ Wmrbf, ushort* __restrict__ W2bf)
{
    const int e = (blockIdx.x * 256 + threadIdx.x) * 4;  // 114688 elems total
    const float* s;
    ushort* d;
    if (e < 16384)      { s = W1 + e;          d = W1bf + e; }
    else if (e < 81920) { s = Wmr + (e-16384); d = Wmrbf + (e-16384); }
    else                { s = W2 + (e-81920);  d = W2bf + (e-81920); }
    const float4 v = *(const float4*)s;
    uint2 r;
    r.x = pk2(v.x, v.y);
    r.y = pk2(v.z, v.w);
    *(uint2*)d = r;
}

// ---------------------------------------------------------------------------
// fc1: xn[n][o] = relu( BN( sum_c W1[o][c]*x[b][c][n] ) )
// block: 512 thr = 8 waves, tile 64 nodes x 128 o; wave w -> o-band 16w.
// A = W1 rows (global, contiguous); B = x^T from LDS; D row=o -> packed
// uint2 stores to xn.  x staged coalesced (2ch x 8n per thread) into
// XOR-swizzled [64][136] u16 tile: u16col ^= (n>>3)<<3 (16B involution).
// Same lb swizzle as mrfc2 so batch b is produced on XCD b.
// ---------------------------------------------------------------------------
__global__ __launch_bounds__(512) void fc1_mfma(
    const float* __restrict__ x, const ushort* __restrict__ W1bf,
    const float* __restrict__ b1, const float* __restrict__ g1,
    const float* __restrict__ be1, const float* __restrict__ m1,
    const float* __restrict__ v1, ushort* __restrict__ xn)
{
    __shared__ __align__(16) ushort xS[64 * 136];   // 17.4 KB
    __shared__ float scS[Cc], shS[Cc];
    const int t = threadIdx.x;
    const int bid = blockIdx.x;
    const int lb = (bid & 7) * 64 + (bid >> 3);     // XCD-local batch mapping
    const int node0 = lb * 64;
    const int b  = node0 >> 12;
    const int n0 = node0 & 4095;

    if (t < Cc) {
        const float s = g1[t] * rsqrtf(v1[t] + EPSf);
        scS[t] = s;
        shS[t] = (b1[t] - m1[t]) * s + be1[t];
    }

    // stage: thread = channels (2cp, 2cp+1) x 8 consecutive n  (coalesced)
    {
        const int cp = t >> 3, q = t & 7;            // n = q*8 .. q*8+7
        const float* p0 = x + ((size_t)(b * Cc + 2 * cp)) * Nn + n0 + q * 8;
        const float* p1 = p0 + Nn;
        const float4 a0 = *(const float4*)(p0);
        const float4 a1 = *(const float4*)(p0 + 4);
        const float4 c0 = *(const float4*)(p1);
        const float4 c1 = *(const float4*)(p1 + 4);
        ushort* base = xS + (size_t)q * 8 * 136 + ((cp * 2) ^ (q << 3));
        *(unsigned*)(base + 0 * 136) = pk2(a0.x, c0.x);
        *(unsigned*)(base + 1 * 136) = pk2(a0.y, c0.y);
        *(unsigned*)(base + 2 * 136) = pk2(a0.z, c0.z);
        *(unsigned*)(base + 3 * 136) = pk2(a0.w, c0.w);
        *(unsigned*)(base + 4 * 136) = pk2(a1.x, c1.x);
        *(unsigned*)(base + 5 * 136) = pk2(a1.y, c1.y);
        *(unsigned*)(base + 6 * 136) = pk2(a1.z, c1.z);
        *(unsigned*)(base + 7 * 136) = pk2(a1.w, c1.w);
    }
    __syncthreads();

    const int w = t >> 6, lane = t & 63;
    const int row16 = lane & 15, kg = lane >> 4;

    f4_t acc[4];  // [nsub]
    const f4_t zero = {0.f, 0.f, 0.f, 0.f};
    #pragma unroll
    for (int j = 0; j < 4; ++j) acc[j] = zero;

    #pragma unroll
    for (int ks = 0; ks < 4; ++ks) {
        const int k0 = ks * 32 + kg * 8;
        const bf8_t aw = *(const bf8_t*)(W1bf + (size_t)(w * 16 + row16) * Cc + k0);
        #pragma unroll
        for (int nsub = 0; nsub < 4; ++nsub) {
            const int n = nsub * 16 + row16;
            const bf8_t bx = *(const bf8_t*)(xS + n * 136 + (k0 ^ ((n >> 3) << 3)));
            acc[nsub] = __builtin_amdgcn_mfma_f32_16x16x32_bf16(aw, bx, acc[nsub], 0, 0, 0);
        }
    }

    // epilogue: lane owns o = o4..o4+3 (consecutive) for 4 node rows -> uint2
    const int o4 = w * 16 + kg * 4;
    const float s0 = scS[o4 + 0], s1 = scS[o4 + 1], s2 = scS[o4 + 2], s3 = scS[o4 + 3];
    const float h0 = shS[o4 + 0], h1 = shS[o4 + 1], h2 = shS[o4 + 2], h3 = shS[o4 + 3];
    #pragma unroll
    for (int nsub = 0; nsub < 4; ++nsub) {
        const int node = node0 + nsub * 16 + row16;
        float v0 = acc[nsub][0] * s0 + h0;
        float v1 = acc[nsub][1] * s1 + h1;
        float v2 = acc[nsub][2] * s2 + h2;
        float v3 = acc[nsub][3] * s3 + h3;
        v0 = v0 > 0.f ? v0 : 0.f;
        v1 = v1 > 0.f ? v1 : 0.f;
        v2 = v2 > 0.f ? v2 : 0.f;
        v3 = v3 > 0.f ? v3 : 0.f;
        uint2 pk;
        pk.x = pk2(v0, v1);
        pk.y = pk2(v2, v3);
        *(uint2*)(xn + (size_t)node * Cc + o4) = pk;
    }
}

// ---------------------------------------------------------------------------
// fused mr+fc2 per 64-node tile, 512 thr = 8 waves:
//   P1: cat = [xn | xn - min_k xn[src]]  -> catS (8 thr/node, 16-ch slices)
//   P2: hn  = relu(Wmr @ cat^T + bmr)    wave j-band 32; packed writeback->catS
//   P3: out = relu( BN(W2 @ hn^T) + x )  wave o-band 16
// XCD swizzle: bid%8 -> batch, so gathers hit XCD-local L2.
// ---------------------------------------------------------------------------
__global__ __launch_bounds__(512) void mrfc2_mfma(
    const ushort* __restrict__ xn, const int* __restrict__ src,
    const ushort* __restrict__ Wmrbf, const float* __restrict__ bmr,
    const ushort* __restrict__ W2bf, const float* __restrict__ x,
    const float* __restrict__ b2, const float* __restrict__ g2,
    const float* __restrict__ be2, const float* __restrict__ m2,
    const float* __restrict__ v2, float* __restrict__ out)
{
    __shared__ __align__(16) ushort catS[64 * 264];  // [node][256] pad->264
    __shared__ int srcS[64 * Kk];
    __shared__ float scS[Cc], shS[Cc];
    const int t = threadIdx.x;
    const int bid = blockIdx.x;
    const int lb = (bid & 7) * 64 + (bid >> 3);      // XCD-local batch mapping
    const int node0 = lb * 64;
    const int b  = node0 >> 12;
    const int n0 = node0 & 4095;

    if (t < Cc) {
        const float s = g2[t] * rsqrtf(v2[t] + EPSf);
        scS[t] = s;
        shS[t] = (b2[t] - m2[t]) * s + be2[t];
    }
    if (t < 256)
        ((int4*)srcS)[t] = ((const int4*)(src + (size_t)node0 * Kk))[t];
    __syncthreads();

    {   // P1: gather + u16-min + diff; 8 threads/node, 16 channels each
        const int nl = t >> 3, q = t & 7;
        const ushort* orow = xn + (size_t)(node0 + nl) * Cc + q * 16;
        uint4 ow0 = *(const uint4*)(orow + 0);
        uint4 ow1 = *(const uint4*)(orow + 8);
        const int* sl = srcS + nl * Kk;
        const ushort* sr = xn + (size_t)sl[0] * Cc + q * 16;
        uint4 mn0 = *(const uint4*)(sr + 0);
        uint4 mn1 = *(const uint4*)(sr + 8);
        #pragma unroll
        for (int k = 1; k < Kk; ++k) {
            const ushort* s = xn + (size_t)sl[k] * Cc + q * 16;
            uint4 v0 = *(const uint4*)(s + 0);
            uint4 v1 = *(const uint4*)(s + 8);
            PKMIN(mn0.x, v0.x); PKMIN(mn0.y, v0.y); PKMIN(mn0.z, v0.z); PKMIN(mn0.w, v0.w);
            PKMIN(mn1.x, v1.x); PKMIN(mn1.y, v1.y); PKMIN(mn1.z, v1.z); PKMIN(mn1.w, v1.w);
        }
        unsigned* crow = (unsigned*)(catS + nl * 264);
        *(uint4*)(crow + q * 8 + 0) = ow0;
        *(uint4*)(crow + q * 8 + 4) = ow1;
        uint4 d0, d1;
        d0.x = diff2(ow0.x, mn0.x); d0.y = diff2(ow0.y, mn0.y);
        d0.z = diff2(ow0.z, mn0.z); d0.w = diff2(ow0.w, mn0.w);
        d1.x = diff2(ow1.x, mn1.x); d1.y = diff2(ow1.y, mn1.y);
        d1.z = diff2(ow1.z, mn1.z); d1.w = diff2(ow1.w, mn1.w);
        *(uint4*)(crow + 64 + q * 8 + 0) = d0;
        *(uint4*)(crow + 64 + q * 8 + 4) = d1;
    }
    __syncthreads();

    const int w = t >> 6, lane = t & 63;
    const int row16 = lane & 15, kg = lane >> 4;

    // ---- P2: hn j-band = relu(Wmr[jb:jb+32] @ cat^T + bmr)  (D: row=j, col=node)
    const int jb = w * 32;
    {
        f4_t acc[2][4];  // [jsub][nsub]
        const f4_t zero = {0.f, 0.f, 0.f, 0.f};
        #pragma unroll
        for (int i = 0; i < 2; ++i)
            #pragma unroll
            for (int j = 0; j < 4; ++j) acc[i][j] = zero;

        #pragma unroll
        for (int ks = 0; ks < 8; ++ks) {
            const int k0 = ks * 32 + kg * 8;
            bf8_t aw[2], bc[4];
            #pragma unroll
            for (int jsub = 0; jsub < 2; ++jsub)
                aw[jsub] = *(const bf8_t*)(Wmrbf + (size_t)(jb + jsub * 16 + row16) * C2 + k0);
            #pragma unroll
            for (int nsub = 0; nsub < 4; ++nsub)
                bc[nsub] = *(const bf8_t*)(catS + (nsub * 16 + row16) * 264 + k0);
            #pragma unroll
            for (int jsub = 0; jsub < 2; ++jsub)
                #pragma unroll
                for (int nsub = 0; nsub < 4; ++nsub)
                    acc[jsub][nsub] = __builtin_amdgcn_mfma_f32_16x16x32_bf16(
                        aw[jsub], bc[nsub], acc[jsub][nsub], 0, 0, 0);
        }
        __syncthreads();  // all P2 reads of catS complete

        // writeback hn into catS: lane's 4 acc rows are consecutive j -> uint2
        #pragma unroll
        for (int jsub = 0; jsub < 2; ++jsub) {
            const float4 bb = *(const float4*)(bmr + jb + jsub * 16 + kg * 4);
            #pragma unroll
            for (int nsub = 0; nsub < 4; ++nsub) {
                float v0 = acc[jsub][nsub][0] + bb.x;
                float v1 = acc[jsub][nsub][1] + bb.y;
                float v2_ = acc[jsub][nsub][2] + bb.z;
                float v3 = acc[jsub][nsub][3] + bb.w;
                v0 = v0 > 0.f ? v0 : 0.f;
                v1 = v1 > 0.f ? v1 : 0.f;
                v2_ = v2_ > 0.f ? v2_ : 0.f;
                v3 = v3 > 0.f ? v3 : 0.f;
                uint2 pk;
                pk.x = pk2(v0, v1);
                pk.y = pk2(v2_, v3);
                *(uint2*)(catS + (nsub * 16 + row16) * 264 + jb + jsub * 16 + kg * 4) = pk;
            }
        }
    }
    __syncthreads();

    // ---- P3: out o-band = relu(BN(W2[ob:ob+16] @ hn^T) + x)  (D: row=o, col=node)
    {
        const int ob = w * 16;
        f4_t acc[4];  // [nsub]
        const f4_t zero = {0.f, 0.f, 0.f, 0.f};
        #pragma unroll
        for (int j = 0; j < 4; ++j) acc[j] = zero;

        #pragma unroll
        for (int ks = 0; ks < 8; ++ks) {
            const int k0 = ks * 32 + kg * 8;
            const bf8_t aw = *(const bf8_t*)(W2bf + (size_t)(ob + row16) * C2 + k0);
            #pragma unroll
            for (int nsub = 0; nsub < 4; ++nsub) {
                const bf8_t bh = *(const bf8_t*)(catS + (nsub * 16 + row16) * 264 + k0);
                acc[nsub] = __builtin_amdgcn_mfma_f32_16x16x32_bf16(aw, bh, acc[nsub], 0, 0, 0);
            }
        }

        #pragma unroll
        for (int r = 0; r < 4; ++r) {
            const int o = ob + kg * 4 + r;
            const float s = scS[o], sh = shS[o];
            const float* xr = x   + ((size_t)(b * Cc + o)) * Nn + n0;
            float*       op = out + ((size_t)(b * Cc + o)) * Nn + n0;
            #pragma unroll
            for (int nsub = 0; nsub < 4; ++nsub) {
                const int nn = nsub * 16 + row16;
                float v = acc[nsub][r] * s + sh + xr[nn];
                v = v > 0.f ? v : 0.f;
                op[nn] = v;
            }
        }
    }
}

// ---------------------------------------------------------------------------
extern "C" void kernel_launch(void* const* d_in, const int* in_sizes, int n_in,
                              void* d_out, int out_size, void* d_ws, size_t ws_size,
                              hipStream_t stream)
{
    const float* x   = (const float*)d_in[0];
    const int*   src = (const int*)  d_in[1];
    const float* W1  = (const float*)d_in[2];
    const float* b1  = (const float*)d_in[3];
    const float* g1  = (const float*)d_in[4];
    const float* be1 = (const float*)d_in[5];
    const float* m1  = (const float*)d_in[6];
    const float* v1  = (const float*)d_in[7];
    const float* Wmr = (const float*)d_in[8];
    const float* bmr = (const float*)d_in[9];
    const float* W2  = (const float*)d_in[10];
    const float* b2  = (const float*)d_in[11];
    const float* g2  = (const float*)d_in[12];
    const float* be2 = (const float*)d_in[13];
    const float* m2  = (const float*)d_in[14];
    const float* v2  = (const float*)d_in[15];
    float* out = (float*)d_out;

    ushort* W1bf  = (ushort*)d_ws;            // 16384
    ushort* Wmrbf = W1bf + 16384;             // 65536
    ushort* W2bf  = Wmrbf + 65536;            // 32768
    ushort* xn    = W2bf + 32768;             // 32768*128

    prep_kernel<<<112, 256, 0, stream>>>(W1, Wmr, W2, W1bf, Wmrbf, W2bf);
    fc1_mfma<<<NODES / 64, 512, 0, stream>>>(x, W1bf, b1, g1, be1, m1, v1, xn);
    mrfc2_mfma<<<NODES / 64, 512, 0, stream>>>(xn, src, Wmrbf, bmr, W2bf, x,
                                               b2, g2, be2, m2, v2, out);
}